// Round 5
// baseline (165.168 us; speedup 1.0000x reference)
//
#include <hip/hip_runtime.h>

#define NTH 256
#define NBOX 16384
#define NCLSIN 91
#define NCLS 90
#define MAXSEL 100
#define TOPK 200
#define TSEL 256      // fallback radix-select size
#define CAP 1024      // candidate list capacity per (b,c)
#define WK 256        // bitmask walk width (bits)
#define BINS 2048
#define GRP 8         // BINS / NTH
#define T0 0.985f     // band threshold: E[hits/class]=246; exact refill guards
#define BOXPB 256     // boxes per filter block
#define KSL 16        // per-class LDS slots per filter block (mean 3.84 hits)
#define OVFC 64       // LDS overflow list capacity
#define CNTSTR 16     // cnt_g stride in ints (64B: one cacheline per counter)

// order-preserving fp32 <-> u32 (strictly monotone for all non-NaN)
__device__ __forceinline__ unsigned fmap(float f) {
    unsigned u = __float_as_uint(f);
    return (u & 0x80000000u) ? ~u : (u | 0x80000000u);
}
__device__ __forceinline__ float funmap(unsigned u) {
    unsigned b = (u & 0x80000000u) ? (u ^ 0x80000000u) : ~u;
    return __uint_as_float(b);
}

// exact reference IoU>0.5 test (same op order, real IEEE div, no FMA)
__device__ __forceinline__ bool sup_test(float4 s, float sa, float4 c, float ca) {
    float y1 = fmaxf(s.x, c.x);
    float x1 = fmaxf(s.y, c.y);
    float y2 = fminf(s.z, c.z);
    float x2 = fminf(s.w, c.w);
    float dy = fmaxf(__fsub_rn(y2, y1), 0.f);
    float dx = fmaxf(__fsub_rn(x2, x1), 0.f);
    float inter = __fmul_rn(dy, dx);
    float uni = __fsub_rn(__fadd_rn(sa, ca), inter);
    return (uni > 0.f) && (__fdiv_rn(inter, uni) > 0.5f);
}

__device__ __forceinline__ void bin_select(unsigned* hist, unsigned* gbuf,
                                           int* sh_g, int* sh_b, unsigned* sh_pb,
                                           int tid, unsigned need) {
    unsigned gs = 0;
#pragma unroll
    for (int q = 0; q < GRP; ++q) gs += hist[tid * GRP + q];
    gbuf[tid] = gs;
    __syncthreads();
    for (int off = 1; off < NTH; off <<= 1) {
        unsigned add = (tid >= off) ? gbuf[tid - off] : 0u;
        __syncthreads();
        gbuf[tid] += add;
        __syncthreads();
    }
    if (tid == 0) *sh_g = NTH - 1;
    __syncthreads();
    if (gbuf[tid] >= need && (tid == 0 || gbuf[tid - 1] < need)) *sh_g = tid;
    __syncthreads();
    if (tid == 0) {
        int g = *sh_g;
        unsigned acc = (g > 0) ? gbuf[g - 1] : 0u;
        int bs = g * GRP + (GRP - 1);
        unsigned pb = acc;
#pragma unroll
        for (int q = 0; q < GRP; ++q) {
            acc += hist[g * GRP + q];
            if (acc >= need) { bs = g * GRP + q; pb = acc; break; }
            pb = acc;
        }
        *sh_b = bs; *sh_pb = pb;
    }
    __syncthreads();
}

// bitonic sort descending of cand[0..M), zero-padded to pow2. Whole block.
__device__ __forceinline__ void sort_desc(unsigned long long* cand, int M, int tid) {
    int P = 1;
    while (P < M) P <<= 1;
    for (int i = M + tid; i < P; i += NTH) cand[i] = 0ull;
    __syncthreads();
    for (int kk = 2; kk <= P; kk <<= 1) {
        for (int jj = kk >> 1; jj > 0; jj >>= 1) {
            for (int i = tid; i < P; i += NTH) {
                int ixj = i ^ jj;
                if (ixj > i) {
                    unsigned long long a = cand[i], c = cand[ixj];
                    bool sw = ((i & kk) == 0) ? (a < c) : (a > c);
                    if (sw) { cand[i] = c; cand[ixj] = a; }
                }
            }
            __syncthreads();
        }
    }
}

// serial greedy walk of sorted cand[from..to) vs LDS selected list (exact,
// rare path). Wave 0 active: lane l tests selbox[l] / selbox[l+64].
__device__ __forceinline__ void serial_walk(
    const unsigned long long* cand, int from, int to,
    const float4* __restrict__ bbase,
    float4* selbox, float* selscore, float* selarea,
    int& nsel, int* sh_nsel, int tid) {
    if (tid < 64) {
        for (int m = from; m < to && nsel < MAXSEL; ++m) {
            unsigned long long key = cand[m];
            float4 bx = bbase[(int)(0xFFFFFFFFu - (unsigned)key)];
            float ca = __fmul_rn(__fsub_rn(bx.z, bx.x), __fsub_rn(bx.w, bx.y));
            bool sup = false;
            if (tid < nsel) sup = sup_test(selbox[tid], selarea[tid], bx, ca);
            int l2 = tid + 64;
            if (l2 < nsel) sup = sup || sup_test(selbox[l2], selarea[l2], bx, ca);
            if (!__any(sup)) {
                if (tid == 0) {
                    selbox[nsel] = bx;
                    selarea[nsel] = ca;
                    selscore[nsel] = funmap((unsigned)(key >> 32));
                }
                nsel++;
            }
        }
        if (tid == 0) *sh_nsel = nsel;
    }
    __syncthreads();
    nsel = *sh_nsel;
    __syncthreads();
}

// ---------------------------------------------------------------------------
// Kernel 0: stream scores once (coalesced float4). Hits (s > T0) stage into
// per-class LDS slots; one parallel global atomicAdd per class per block.
// ---------------------------------------------------------------------------
__global__ __launch_bounds__(NTH) void filter_k(const float* __restrict__ in,
                                                unsigned long long* __restrict__ cand_g,
                                                int* __restrict__ cnt_g) {
    __shared__ int cnt_s[NCLSIN];
    __shared__ int base_s[NCLSIN];
    __shared__ unsigned long long ent[NCLSIN * KSL];
    __shared__ unsigned ovf_meta[OVFC];
    __shared__ unsigned long long ovf_key[OVFC];
    __shared__ int sh_ovf;

    const int tid = threadIdx.x;
    const int n0 = blockIdx.x * BOXPB;
    const int b = blockIdx.y;
    const int NF4 = BOXPB * NCLSIN / 4;

    for (int i = tid; i < NCLSIN; i += NTH) cnt_s[i] = 0;
    if (tid == 0) sh_ovf = 0;
    __syncthreads();

    const float4* src = (const float4*)(in + ((size_t)b * NBOX + n0) * NCLSIN);
    for (int t = tid; t < NF4; t += NTH) {
        float4 v = src[t];
        float mx = fmaxf(fmaxf(v.x, v.y), fmaxf(v.z, v.w));
        if (mx > T0) {
            const float sv[4] = {v.x, v.y, v.z, v.w};
            int e = t * 4;
#pragma unroll
            for (int q = 0; q < 4; ++q) {
                float s = sv[q];
                if (s > T0) {
                    int ee = e + q;
                    int row = ee / NCLSIN;
                    int c = ee - row * NCLSIN;
                    if (c) {
                        int r = atomicAdd(&cnt_s[c], 1);
                        unsigned i = (unsigned)(n0 + row);
                        unsigned long long key =
                            ((unsigned long long)fmap(s) << 32) | (0xFFFFFFFFu - i);
                        if (r < KSL) {
                            ent[c * KSL + r] = key;
                        } else {
                            int o = atomicAdd(&sh_ovf, 1);
                            if (o < OVFC) {
                                ovf_meta[o] = ((unsigned)c << 16) | (unsigned)r;
                                ovf_key[o] = key;
                            } else {
                                atomicAdd(&cnt_g[(b * NCLS + c - 1) * CNTSTR], CAP + 1);
                            }
                        }
                    }
                }
            }
        }
    }
    __syncthreads();

    if (tid >= 1 && tid < NCLSIN) {
        int c = tid;
        int n = cnt_s[c];
        int base = 0;
        if (n > 0) {
            int bc = b * NCLS + c - 1;
            base = atomicAdd(&cnt_g[bc * CNTSTR], n);
            int lim = n < KSL ? n : KSL;
            for (int j = 0; j < lim; ++j) {
                int pos = base + j;
                if (pos < CAP) cand_g[(size_t)bc * CAP + pos] = ent[c * KSL + j];
            }
        }
        base_s[c] = base;
    }
    __syncthreads();

    int no = sh_ovf < OVFC ? sh_ovf : OVFC;
    for (int o = tid; o < no; o += NTH) {
        unsigned m = ovf_meta[o];
        int c = (int)(m >> 16);
        int r = (int)(m & 0xFFFFu);
        int bc = b * NCLS + c - 1;
        int pos = base_s[c] + r;
        if (pos < CAP) cand_g[(size_t)bc * CAP + pos] = ovf_key[o];
    }
}

// ---------------------------------------------------------------------------
// Kernel 1: one block per (batch, class). Sort band -> parallel pairwise
// suppression bit-matrix -> single-lane bitmask greedy walk. Serial-walk
// tail for C>WK; adaptive radix-select global refill preserves exactness.
// ---------------------------------------------------------------------------
__global__ __launch_bounds__(NTH) void nms_k(
    const unsigned long long* __restrict__ cand_g,
    const int* __restrict__ cnt_g,
    const float* __restrict__ scores_raw,
    const float4* __restrict__ boxes,
    float* __restrict__ ws_sc, float* __restrict__ ws_bx, int use_band) {
    __shared__ unsigned long long cand[CAP];        // 8 KB
    __shared__ float4 candbox[WK];                  // 4 KB
    __shared__ float carea[WK];                     // 1 KB
    __shared__ unsigned long long colmask[WK * 4];  // 8 KB (= hist in fallback)
    __shared__ float4 selbox[MAXSEL];
    __shared__ float selscore[MAXSEL];
    __shared__ float selarea[MAXSEL];
    __shared__ int sellist[MAXSEL];
    __shared__ unsigned gbuf[NTH];
    __shared__ unsigned sh_kmax, sh_pb;
    __shared__ int sh_E, sh_g, sh_b, sh_cnt, sh_nsel;
    unsigned* hist = (unsigned*)colmask;  // colmask dead before fallback uses hist

    const int tid = threadIdx.x;
    const int c0 = blockIdx.x;
    const int b = blockIdx.y;
    const int bc = b * NCLS + c0;
    const float* sraw = scores_raw + (size_t)b * NBOX * NCLSIN + (c0 + 1);
    const float4* bbase = boxes + (size_t)b * NBOX;

    int nsel = 0;
    unsigned long long lastk = ~0ull;

    if (use_band) {
        const int C = cnt_g[bc * CNTSTR];
        if (C > 0 && C <= CAP) {
            for (int i = tid; i < C; i += NTH)
                cand[i] = cand_g[(size_t)bc * CAP + i];
            sort_desc(cand, C, tid);
            const int WKm = C < WK ? C : WK;
            for (int i = tid; i < WKm; i += NTH) {
                float4 bx = bbase[(int)(0xFFFFFFFFu - (unsigned)cand[i])];
                candbox[i] = bx;
                carea[i] = __fmul_rn(__fsub_rn(bx.z, bx.x), __fsub_rn(bx.w, bx.y));
            }
            __syncthreads();

            // pairwise forward-suppression matrix: thread t = column t,
            // bit j set iff selected-j would suppress t (j < t, sorted order)
            {
                float4 mybx = make_float4(0.f, 0.f, 0.f, 0.f);
                float mya = 0.f;
                int lim = 0;
                if (tid < WKm) { mybx = candbox[tid]; mya = carea[tid]; lim = tid; }
#pragma unroll
                for (int c = 0; c < 4; ++c) {
                    unsigned long long mm = 0ull;
                    int j1 = lim < (c + 1) * 64 ? lim : (c + 1) * 64;
                    for (int j = c * 64; j < j1; ++j)
                        if (sup_test(candbox[j], carea[j], mybx, mya))
                            mm |= 1ull << (j - c * 64);
                    colmask[tid * 4 + c] = mm;  // c compile-time (unrolled)
                }
            }
            __syncthreads();

            // single-lane bitmask greedy walk: ~15 cy/iter, reads independent
            // of selection state (pipelineable)
            if (tid == 0) {
                unsigned long long sb0 = 0, sb1 = 0, sb2 = 0, sb3 = 0;
                int ns = 0;
                for (int m = 0; m < WKm; ++m) {
                    const unsigned long long* cm = &colmask[m * 4];
                    unsigned long long hit = (cm[0] & sb0) | (cm[1] & sb1) |
                                             (cm[2] & sb2) | (cm[3] & sb3);
                    if (!hit) {
                        sellist[ns++] = m;
                        unsigned long long bit = 1ull << (m & 63);
                        int cc = m >> 6;
                        if (cc == 0) sb0 |= bit;
                        else if (cc == 1) sb1 |= bit;
                        else if (cc == 2) sb2 |= bit;
                        else sb3 |= bit;
                        if (ns >= MAXSEL) break;
                    }
                }
                sh_nsel = ns;
            }
            __syncthreads();
            nsel = sh_nsel;
            for (int k = tid; k < nsel; k += NTH) {
                int m = sellist[k];
                selscore[k] = funmap((unsigned)(cand[m] >> 32));
                selbox[k] = candbox[m];
                selarea[k] = carea[m];
            }
            __syncthreads();
            if (nsel < MAXSEL && C > WK)
                serial_walk(cand, WK, C, bbase, selbox, selscore, selarea,
                            nsel, &sh_nsel, tid);
            lastk = cand[C - 1];  // smallest examined key
        }
        // C==0 or C>CAP: lastk stays ~0 -> exact full fallback below
    }

    while (nsel < MAXSEL) {
        // ---- eligible count + max key (keys strictly below lastk) ----
        unsigned km = 0, ce = 0;
        for (int i = tid; i < NBOX; i += NTH) {
            float s = sraw[(size_t)i * NCLSIN];
            unsigned k = (s > 0.3f) ? fmap(s) : 0u;
            if (k) {
                unsigned long long key =
                    ((unsigned long long)k << 32) | (0xFFFFFFFFu - (unsigned)i);
                if (key < lastk) { ce++; km = km > k ? km : k; }
            }
        }
#pragma unroll
        for (int off = 32; off > 0; off >>= 1) {
            unsigned o = (unsigned)__shfl_xor((int)km, off, 64);
            km = km > o ? km : o;
            ce += (unsigned)__shfl_xor((int)ce, off, 64);
        }
        if ((tid & 63) == 0) { gbuf[tid >> 6] = km; gbuf[8 + (tid >> 6)] = ce; }
        __syncthreads();
        if (tid == 0) {
            unsigned m2 = 0, c2 = 0;
            for (int w = 0; w < NTH / 64; ++w) {
                m2 = m2 > gbuf[w] ? m2 : gbuf[w];
                c2 += gbuf[8 + w];
            }
            sh_kmax = m2; sh_E = (int)c2;
        }
        __syncthreads();
        const int E = sh_E;
        const unsigned kmax = sh_kmax;
        if (E == 0) break;

        unsigned thr = 1u;
        if (E > TSEL) {
            for (int shift = 8;; shift += 4) {
                for (int i = tid; i < BINS; i += NTH) hist[i] = 0u;
                __syncthreads();
                for (int i = tid; i < NBOX; i += NTH) {
                    float s = sraw[(size_t)i * NCLSIN];
                    unsigned k = (s > 0.3f) ? fmap(s) : 0u;
                    if (k) {
                        unsigned long long key =
                            ((unsigned long long)k << 32) | (0xFFFFFFFFu - (unsigned)i);
                        if (key < lastk) {
                            unsigned bin = (kmax - k) >> shift;
                            if (bin < BINS - 1) atomicAdd(&hist[bin], 1u);
                        }
                    }
                }
                __syncthreads();
                bin_select(hist, gbuf, &sh_g, &sh_b, &sh_pb, tid, (unsigned)TSEL);
                if (sh_b < BINS - 1) {
                    long long t = (long long)kmax - ((long long)(sh_b + 1) << shift) + 1;
                    thr = (t < 1) ? 1u : (unsigned)t;
                    break;
                }
            }
        }

        if (tid == 0) sh_cnt = 0;
        __syncthreads();
        for (int i = tid; i < NBOX; i += NTH) {
            float s = sraw[(size_t)i * NCLSIN];
            unsigned k = (s > 0.3f) ? fmap(s) : 0u;
            if (k >= thr) {
                unsigned long long key =
                    ((unsigned long long)k << 32) | (0xFFFFFFFFu - (unsigned)i);
                if (key < lastk) {
                    int pos = atomicAdd(&sh_cnt, 1);
                    if (pos < CAP) cand[pos] = key;
                }
            }
        }
        __syncthreads();
        const int M = sh_cnt < CAP ? sh_cnt : CAP;

        sort_desc(cand, M, tid);
        serial_walk(cand, 0, M, bbase, selbox, selscore, selarea,
                    nsel, &sh_nsel, tid);
        if (nsel >= MAXSEL || E <= M) break;
        lastk = cand[M - 1];
        __syncthreads();
    }

    // ---- outputs: selections in greedy order, zero-padded ----
    if (tid < MAXSEL) {
        bool v = tid < nsel;
        ws_sc[(size_t)bc * MAXSEL + tid] = v ? selscore[tid] : 0.f;
        ((float4*)ws_bx)[(size_t)bc * MAXSEL + tid] =
            v ? selbox[tid] : make_float4(0.f, 0.f, 0.f, 0.f);
    }
}

// ---------------------------------------------------------------------------
// Kernel 2: one block per batch: stable top-200 of 9000 via radix-select+sort.
// ---------------------------------------------------------------------------
__global__ __launch_bounds__(NTH) void topk_k(const float* __restrict__ ws_sc,
                                              const float* __restrict__ ws_bx,
                                              float* __restrict__ out_sc,
                                              float* __restrict__ out_bx) {
    __shared__ unsigned hist[BINS];
    __shared__ unsigned gbuf[NTH];
    __shared__ unsigned long long cand[CAP];
    __shared__ unsigned sh_kmax, sh_pb;
    __shared__ int sh_E, sh_g, sh_b, sh_cnt;

    const int tid = threadIdx.x;
    const int b = blockIdx.x;
    const int NF = NCLS * MAXSEL;  // 9000
    const float* sp = ws_sc + (size_t)b * NF;

    unsigned km = 0, ce = 0;
    for (int f = tid; f < NF; f += NTH) {
        unsigned k = __float_as_uint(sp[f]);
        if (k) { ce++; km = km > k ? km : k; }
    }
#pragma unroll
    for (int off = 32; off > 0; off >>= 1) {
        unsigned o = (unsigned)__shfl_xor((int)km, off, 64);
        km = km > o ? km : o;
        ce += (unsigned)__shfl_xor((int)ce, off, 64);
    }
    if ((tid & 63) == 0) { gbuf[tid >> 6] = km; gbuf[8 + (tid >> 6)] = ce; }
    __syncthreads();
    if (tid == 0) {
        unsigned m2 = 0, c2 = 0;
        for (int w = 0; w < NTH / 64; ++w) {
            m2 = m2 > gbuf[w] ? m2 : gbuf[w];
            c2 += gbuf[8 + w];
        }
        sh_kmax = m2; sh_E = (int)c2;
    }
    __syncthreads();
    const int E = sh_E;
    const unsigned kmax = sh_kmax;

    unsigned thr = 1u;
    if (E > TOPK) {
        for (int shift = 8;; shift += 4) {
            for (int i = tid; i < BINS; i += NTH) hist[i] = 0u;
            __syncthreads();
            for (int f = tid; f < NF; f += NTH) {
                unsigned k = __float_as_uint(sp[f]);
                if (k) {
                    unsigned bin = (kmax - k) >> shift;
                    if (bin < BINS - 1) atomicAdd(&hist[bin], 1u);
                }
            }
            __syncthreads();
            bin_select(hist, gbuf, &sh_g, &sh_b, &sh_pb, tid, (unsigned)TOPK);
            if (sh_b < BINS - 1) {
                long long t = (long long)kmax - ((long long)(sh_b + 1) << shift) + 1;
                thr = (t < 1) ? 1u : (unsigned)t;
                break;
            }
        }
    }

    if (tid == 0) sh_cnt = 0;
    __syncthreads();
    for (int f = tid; f < NF; f += NTH) {
        unsigned k = __float_as_uint(sp[f]);
        if (k >= thr) {
            int pos = atomicAdd(&sh_cnt, 1);
            if (pos < CAP)
                cand[pos] = ((unsigned long long)k << 32) | (0xFFFFFFFFu - (unsigned)f);
        }
    }
    __syncthreads();
    int M = sh_cnt < CAP ? sh_cnt : CAP;

    if (M < TOPK) {
        int lim = M + TOPK;
        if (lim > NF) lim = NF;
        for (int f = tid; f < lim; f += NTH) {
            unsigned k = __float_as_uint(sp[f]);
            if (k == 0) {
                int pos = atomicAdd(&sh_cnt, 1);
                if (pos < CAP)
                    cand[pos] = (unsigned long long)(0xFFFFFFFFu - (unsigned)f);
            }
        }
        __syncthreads();
        M = sh_cnt < CAP ? sh_cnt : CAP;
    }

    sort_desc(cand, M, tid);

    for (int k = tid; k < TOPK; k += NTH) {
        float cls = 0.f, s = 0.f;
        float4 bx = make_float4(0.f, 0.f, 0.f, 0.f);
        if (k < M) {
            unsigned long long key = cand[k];
            unsigned f = 0xFFFFFFFFu - (unsigned)key;
            s = __uint_as_float((unsigned)(key >> 32));
            cls = (s > 0.f) ? (float)(f / MAXSEL + 1) : 0.f;
            bx = *(const float4*)(ws_bx + ((size_t)b * NF + f) * 4);
        }
        out_sc[((size_t)b * TOPK + k) * 2 + 0] = cls;
        out_sc[((size_t)b * TOPK + k) * 2 + 1] = s;
        ((float4*)out_bx)[(size_t)b * TOPK + k] = bx;
    }
}

// ---------------------------------------------------------------------------
extern "C" void kernel_launch(void* const* d_in, const int* in_sizes, int n_in,
                              void* d_out, int out_size, void* d_ws, size_t ws_size,
                              hipStream_t stream) {
    const float* scores = (const float*)d_in[0];
    const float4* boxes = (const float4*)d_in[1];
    float* out = (float*)d_out;

    const int B = in_sizes[1] / (NBOX * 4);
    const int NBC = B * NCLS;

    // ws layout: cnt [NBC * CNTSTR ints, 64B-padded] | cand [NBC*CAP u64] | sc | bx
    size_t off_cand = ((size_t)NBC * CNTSTR * 4 + 15) & ~(size_t)15;
    size_t off_sc = off_cand + (size_t)NBC * CAP * 8;
    size_t off_bx = off_sc + (size_t)NBC * MAXSEL * 4;
    size_t need = off_bx + (size_t)NBC * MAXSEL * 16;

    char* ws = (char*)d_ws;
    bool use_band = ws_size >= need;

    int* cnt_g;
    unsigned long long* cand_g;
    float *ws_sc, *ws_bx;
    if (use_band) {
        cnt_g = (int*)ws;
        cand_g = (unsigned long long*)(ws + off_cand);
        ws_sc = (float*)(ws + off_sc);
        ws_bx = (float*)(ws + off_bx);
    } else {
        cnt_g = (int*)ws;                  // unused
        cand_g = (unsigned long long*)ws;  // unused
        ws_sc = (float*)ws;
        ws_bx = ws_sc + (size_t)NBC * MAXSEL;
    }

    if (use_band) {
        hipMemsetAsync(cnt_g, 0, (size_t)NBC * CNTSTR * 4, stream);
        filter_k<<<dim3(NBOX / BOXPB, B), NTH, 0, stream>>>(scores, cand_g, cnt_g);
    }
    nms_k<<<dim3(NCLS, B), NTH, 0, stream>>>(cand_g, cnt_g, scores, boxes,
                                             ws_sc, ws_bx, use_band ? 1 : 0);
    topk_k<<<B, NTH, 0, stream>>>(ws_sc, ws_bx, out, out + (size_t)B * TOPK * 2);
}

// Round 6
// 132.003 us; speedup vs baseline: 1.2512x; 1.2512x over previous
//
#include <hip/hip_runtime.h>

#define NTH 256
#define NBOX 16384
#define NCLSIN 91
#define NCLS 90
#define MAXSEL 100
#define TOPK 200
#define TSEL 256      // fallback radix-select size
#define CAP 1024      // candidate list capacity per (b,c)
#define CBCAP 384     // prefetched candidate boxes (band C ~ 246 +- 16)
#define BINS 1024
#define GRP 4         // BINS / NTH
#define T0 0.985f     // band threshold: E[hits/class]=246; exact refill guards
#define BOXPB 256     // boxes per filter block
#define KSL 16        // per-class LDS slots per filter block (mean 3.84 hits)
#define OVFC 64       // LDS overflow list capacity
#define CNTSTR 16     // cnt_g stride in ints (64B: one cacheline per counter)

// order-preserving fp32 <-> u32 (strictly monotone for all non-NaN)
__device__ __forceinline__ unsigned fmap(float f) {
    unsigned u = __float_as_uint(f);
    return (u & 0x80000000u) ? ~u : (u | 0x80000000u);
}
__device__ __forceinline__ float funmap(unsigned u) {
    unsigned b = (u & 0x80000000u) ? (u ^ 0x80000000u) : ~u;
    return __uint_as_float(b);
}

// exact reference IoU>0.5 test (same op order, real IEEE div, no FMA)
__device__ __forceinline__ bool sup_test(float4 s, float sa, float4 c, float ca) {
    float y1 = fmaxf(s.x, c.x);
    float x1 = fmaxf(s.y, c.y);
    float y2 = fminf(s.z, c.z);
    float x2 = fminf(s.w, c.w);
    float dy = fmaxf(__fsub_rn(y2, y1), 0.f);
    float dx = fmaxf(__fsub_rn(x2, x1), 0.f);
    float inter = __fmul_rn(dy, dx);
    float uni = __fsub_rn(__fadd_rn(sa, ca), inter);
    return (uni > 0.f) && (__fdiv_rn(inter, uni) > 0.5f);
}

__device__ __forceinline__ void bin_select(unsigned* hist, unsigned* gbuf,
                                           int* sh_g, int* sh_b, unsigned* sh_pb,
                                           int tid, unsigned need) {
    unsigned gs = 0;
#pragma unroll
    for (int q = 0; q < GRP; ++q) gs += hist[tid * GRP + q];
    gbuf[tid] = gs;
    __syncthreads();
    for (int off = 1; off < NTH; off <<= 1) {
        unsigned add = (tid >= off) ? gbuf[tid - off] : 0u;
        __syncthreads();
        gbuf[tid] += add;
        __syncthreads();
    }
    if (tid == 0) *sh_g = NTH - 1;
    __syncthreads();
    if (gbuf[tid] >= need && (tid == 0 || gbuf[tid - 1] < need)) *sh_g = tid;
    __syncthreads();
    if (tid == 0) {
        int g = *sh_g;
        unsigned acc = (g > 0) ? gbuf[g - 1] : 0u;
        int bs = g * GRP + (GRP - 1);
        unsigned pb = acc;
#pragma unroll
        for (int q = 0; q < GRP; ++q) {
            acc += hist[g * GRP + q];
            if (acc >= need) { bs = g * GRP + q; pb = acc; break; }
            pb = acc;
        }
        *sh_b = bs; *sh_pb = pb;
    }
    __syncthreads();
}

// bitonic sort descending of cand[0..M), zero-padded to pow2. Whole block.
__device__ __forceinline__ void sort_desc(unsigned long long* cand, int M, int tid) {
    int P = 1;
    while (P < M) P <<= 1;
    for (int i = M + tid; i < P; i += NTH) cand[i] = 0ull;
    __syncthreads();
    for (int kk = 2; kk <= P; kk <<= 1) {
        for (int jj = kk >> 1; jj > 0; jj >>= 1) {
            for (int i = tid; i < P; i += NTH) {
                int ixj = i ^ jj;
                if (ixj > i) {
                    unsigned long long a = cand[i], c = cand[ixj];
                    bool sw = ((i & kk) == 0) ? (a < c) : (a > c);
                    if (sw) { cand[i] = c; cand[ixj] = a; }
                }
            }
            __syncthreads();
        }
    }
}

// ---------------------------------------------------------------------------
// filter_k helper: route one hit (pk = fmap(score)<<32 | ee) into per-class
// LDS staging. Exact; c==0 (background) skipped.
// ---------------------------------------------------------------------------
__device__ __forceinline__ void emit_hit(unsigned long long pk, int b, int n0,
                                         int* cnt_s, unsigned long long* ent,
                                         unsigned* ovf_meta,
                                         unsigned long long* ovf_key,
                                         int* sh_ovf, int* cnt_g) {
    unsigned ee = (unsigned)pk;
    int row = (int)ee / NCLSIN;        // magic-mul
    int c = (int)ee - row * NCLSIN;
    if (c == 0) return;                // background class
    unsigned i = (unsigned)(n0 + row);
    unsigned long long key = (pk & 0xFFFFFFFF00000000ull) | (0xFFFFFFFFu - i);
    int r = atomicAdd(&cnt_s[c], 1);
    if (r < KSL) {
        ent[c * KSL + r] = key;
    } else {
        int o = atomicAdd(sh_ovf, 1);
        if (o < OVFC) {
            ovf_meta[o] = ((unsigned)c << 16) | (unsigned)r;
            ovf_key[o] = key;
        } else {
            // astronomically rare: force exact full fallback for this class
            atomicAdd(&cnt_g[(b * NCLS + c - 1) * CNTSTR], CAP + 1);
        }
    }
}

// ---------------------------------------------------------------------------
// Kernel 0: stream scores once (2x float4 per lane). Hits buffered in 4
// per-lane registers (static slots), drained once at end; >=5th hit spills
// to the exact immediate path. One global atomicAdd per class per block.
// ---------------------------------------------------------------------------
__global__ __launch_bounds__(NTH) void filter_k(const float* __restrict__ in,
                                                unsigned long long* __restrict__ cand_g,
                                                int* __restrict__ cnt_g) {
    __shared__ int cnt_s[NCLSIN];
    __shared__ int base_s[NCLSIN];
    __shared__ unsigned long long ent[NCLSIN * KSL];
    __shared__ unsigned ovf_meta[OVFC];
    __shared__ unsigned long long ovf_key[OVFC];
    __shared__ int sh_ovf;

    const int tid = threadIdx.x;
    const int n0 = blockIdx.x * BOXPB;
    const int b = blockIdx.y;
    const int NF4 = BOXPB * NCLSIN / 4;  // 5824 float4 per block

    for (int i = tid; i < NCLSIN; i += NTH) cnt_s[i] = 0;
    if (tid == 0) sh_ovf = 0;
    __syncthreads();

    unsigned long long q0 = 0, q1 = 0, q2 = 0, q3 = 0;
    int lc = 0;

    const float4* src = (const float4*)(in + ((size_t)b * NBOX + n0) * NCLSIN);
    for (int i = tid; i < NF4; i += 2 * NTH) {
        float4 v1 = src[i];
        int i2 = i + NTH;
        bool has2 = i2 < NF4;
        float4 v2 = make_float4(0.f, 0.f, 0.f, 0.f);
        if (has2) v2 = src[i2];
        float mx1 = fmaxf(fmaxf(v1.x, v1.y), fmaxf(v1.z, v1.w));
        float mx2 = fmaxf(fmaxf(v2.x, v2.y), fmaxf(v2.z, v2.w));
        if (fmaxf(mx1, mx2) > T0) {
#pragma unroll
            for (int h = 0; h < 2; ++h) {
                float4 v = h ? v2 : v1;
                float mx = h ? mx2 : mx1;
                int eb = (h ? i2 : i) * 4;
                if (mx > T0) {
                    const float sv[4] = {v.x, v.y, v.z, v.w};
#pragma unroll
                    for (int qq = 0; qq < 4; ++qq) {
                        float s = sv[qq];
                        if (s > T0) {
                            unsigned long long pk =
                                ((unsigned long long)fmap(s) << 32) |
                                (unsigned)(eb + qq);
                            if (lc == 0) q0 = pk;
                            else if (lc == 1) q1 = pk;
                            else if (lc == 2) q2 = pk;
                            else if (lc == 3) q3 = pk;
                            else emit_hit(pk, b, n0, cnt_s, ent, ovf_meta,
                                          ovf_key, &sh_ovf, cnt_g);
                            ++lc;
                        }
                    }
                }
            }
        }
    }
    // drain register queue (rare per-lane, cheap once per block)
    if (lc > 0) emit_hit(q0, b, n0, cnt_s, ent, ovf_meta, ovf_key, &sh_ovf, cnt_g);
    if (lc > 1) emit_hit(q1, b, n0, cnt_s, ent, ovf_meta, ovf_key, &sh_ovf, cnt_g);
    if (lc > 2) emit_hit(q2, b, n0, cnt_s, ent, ovf_meta, ovf_key, &sh_ovf, cnt_g);
    if (lc > 3) emit_hit(q3, b, n0, cnt_s, ent, ovf_meta, ovf_key, &sh_ovf, cnt_g);
    __syncthreads();

    // Phase B: one atomic per non-empty class, all issued in parallel
    if (tid >= 1 && tid < NCLSIN) {
        int c = tid;
        int n = cnt_s[c];
        int base = 0;
        if (n > 0) {
            int bc = b * NCLS + c - 1;
            base = atomicAdd(&cnt_g[bc * CNTSTR], n);
            int lim = n < KSL ? n : KSL;
            for (int j = 0; j < lim; ++j) {
                int pos = base + j;
                if (pos < CAP) cand_g[(size_t)bc * CAP + pos] = ent[c * KSL + j];
            }
        }
        base_s[c] = base;
    }
    __syncthreads();

    int no = sh_ovf < OVFC ? sh_ovf : OVFC;
    for (int o = tid; o < no; o += NTH) {
        unsigned m = ovf_meta[o];
        int c = (int)(m >> 16);
        int r = (int)(m & 0xFFFFu);
        int bc = b * NCLS + c - 1;
        int pos = base_s[c] + r;
        if (pos < CAP) cand_g[(size_t)bc * CAP + pos] = ovf_key[o];
    }
}

// ---------------------------------------------------------------------------
// Greedy walk, wave 0 only. Selected boxes live in 2 register slots per lane.
// walk_fast: software-pipelined (prefetch m+1 before ballot of m), requires
// all boxes prefetched in candbox (M <= CBCAP).
// ---------------------------------------------------------------------------
__device__ __forceinline__ void walk_fast(
    const unsigned long long* cand, const float4* candbox, int M,
    float4& sel0, float4& sel1, float& sa0, float& sa1,
    float& ss0, float& ss1, int& nsel, int* sh_nsel, int tid) {
    if (tid < 64) {
        unsigned long long key_c = cand[0];
        float4 bx_c = candbox[0];
        for (int m = 0; m < M; ++m) {
            int mn = (m + 1 < M) ? m + 1 : m;
            unsigned long long key_n = cand[mn];  // prefetch next (hides LDS lat)
            float4 bx_n = candbox[mn];
            float ca = __fmul_rn(__fsub_rn(bx_c.z, bx_c.x), __fsub_rn(bx_c.w, bx_c.y));
            bool sup = false;
            if (tid < nsel) sup = sup_test(sel0, sa0, bx_c, ca);
            if (tid + 64 < nsel) sup = sup || sup_test(sel1, sa1, bx_c, ca);
            if (!__any(sup)) {
                if (tid == nsel) { sel0 = bx_c; sa0 = ca; ss0 = funmap((unsigned)(key_c >> 32)); }
                if (tid == nsel - 64) { sel1 = bx_c; sa1 = ca; ss1 = funmap((unsigned)(key_c >> 32)); }
                nsel++;
                if (nsel >= MAXSEL) break;
            }
            key_c = key_n;
            bx_c = bx_n;
        }
        if (tid == 0) *sh_nsel = nsel;
    }
    __syncthreads();
    nsel = *sh_nsel;
    __syncthreads();
}

// walk_slow: unpipelined, global-fetch fallback beyond CBCAP (rare paths)
__device__ __forceinline__ void walk_slow(
    const unsigned long long* cand, int from, int to,
    const float4* __restrict__ bbase, const float4* candbox,
    float4& sel0, float4& sel1, float& sa0, float& sa1,
    float& ss0, float& ss1, int& nsel, int* sh_nsel, int tid) {
    if (tid < 64) {
        for (int m = from; m < to && nsel < MAXSEL; ++m) {
            unsigned long long key = cand[m];
            float4 bx = (m < CBCAP) ? candbox[m]
                                    : bbase[(int)(0xFFFFFFFFu - (unsigned)key)];
            float ca = __fmul_rn(__fsub_rn(bx.z, bx.x), __fsub_rn(bx.w, bx.y));
            bool sup = false;
            if (tid < nsel) sup = sup_test(sel0, sa0, bx, ca);
            if (tid + 64 < nsel) sup = sup || sup_test(sel1, sa1, bx, ca);
            if (!__any(sup)) {
                if (tid == nsel) { sel0 = bx; sa0 = ca; ss0 = funmap((unsigned)(key >> 32)); }
                if (tid == nsel - 64) { sel1 = bx; sa1 = ca; ss1 = funmap((unsigned)(key >> 32)); }
                nsel++;
            }
        }
        if (tid == 0) *sh_nsel = nsel;
    }
    __syncthreads();
    nsel = *sh_nsel;
    __syncthreads();
}

// ---------------------------------------------------------------------------
// Kernel 1: one block per (batch, class). Sort band -> pipelined register
// walk. Exact refill via adaptive radix-select over raw strided scores.
// ---------------------------------------------------------------------------
__global__ __launch_bounds__(NTH) void nms_k(
    const unsigned long long* __restrict__ cand_g,
    const int* __restrict__ cnt_g,
    const float* __restrict__ scores_raw,
    const float4* __restrict__ boxes,
    float* __restrict__ ws_sc, float* __restrict__ ws_bx, int use_band) {
    __shared__ unsigned long long cand[CAP];   // 8 KB
    __shared__ float4 candbox[CBCAP];          // 6 KB (aliased as hist in fallback)
    __shared__ unsigned gbuf[NTH];             // 1 KB
    __shared__ unsigned sh_kmax, sh_pb;
    __shared__ int sh_E, sh_g, sh_b, sh_cnt, sh_nsel;
    unsigned* hist = (unsigned*)candbox;  // candbox dead while hist live

    const int tid = threadIdx.x;
    const int c0 = blockIdx.x;
    const int b = blockIdx.y;
    const int bc = b * NCLS + c0;
    const float* sraw = scores_raw + (size_t)b * NBOX * NCLSIN + (c0 + 1);
    const float4* bbase = boxes + (size_t)b * NBOX;

    float4 sel0 = make_float4(0.f, 0.f, 0.f, 0.f);
    float4 sel1 = make_float4(0.f, 0.f, 0.f, 0.f);
    float sa0 = 0.f, sa1 = 0.f, ss0 = 0.f, ss1 = 0.f;
    int nsel = 0;
    unsigned long long lastk = ~0ull;

    if (use_band) {
        const int C = cnt_g[bc * CNTSTR];
        if (C > 0 && C <= CAP) {
            for (int i = tid; i < C; i += NTH)
                cand[i] = cand_g[(size_t)bc * CAP + i];
            sort_desc(cand, C, tid);
            const int PBX = C < CBCAP ? C : CBCAP;
            for (int i = tid; i < PBX; i += NTH)
                candbox[i] = bbase[(int)(0xFFFFFFFFu - (unsigned)cand[i])];
            __syncthreads();
            if (C <= CBCAP)
                walk_fast(cand, candbox, C, sel0, sel1, sa0, sa1,
                          ss0, ss1, nsel, &sh_nsel, tid);
            else
                walk_slow(cand, 0, C, bbase, candbox, sel0, sel1, sa0, sa1,
                          ss0, ss1, nsel, &sh_nsel, tid);
            lastk = cand[C - 1];  // smallest examined key
        }
        // C==0 or C>CAP: lastk stays ~0 -> exact full fallback below
    }

    while (nsel < MAXSEL) {
        // ---- eligible count + max key (keys strictly below lastk) ----
        unsigned km = 0, ce = 0;
        for (int i = tid; i < NBOX; i += NTH) {
            float s = sraw[(size_t)i * NCLSIN];
            unsigned k = (s > 0.3f) ? fmap(s) : 0u;
            if (k) {
                unsigned long long key =
                    ((unsigned long long)k << 32) | (0xFFFFFFFFu - (unsigned)i);
                if (key < lastk) { ce++; km = km > k ? km : k; }
            }
        }
#pragma unroll
        for (int off = 32; off > 0; off >>= 1) {
            unsigned o = (unsigned)__shfl_xor((int)km, off, 64);
            km = km > o ? km : o;
            ce += (unsigned)__shfl_xor((int)ce, off, 64);
        }
        if ((tid & 63) == 0) { gbuf[tid >> 6] = km; gbuf[8 + (tid >> 6)] = ce; }
        __syncthreads();
        if (tid == 0) {
            unsigned m2 = 0, c2 = 0;
            for (int w = 0; w < NTH / 64; ++w) {
                m2 = m2 > gbuf[w] ? m2 : gbuf[w];
                c2 += gbuf[8 + w];
            }
            sh_kmax = m2; sh_E = (int)c2;
        }
        __syncthreads();
        const int E = sh_E;
        const unsigned kmax = sh_kmax;
        if (E == 0) break;

        unsigned thr = 1u;
        if (E > TSEL) {
            for (int shift = 8;; shift += 4) {
                for (int i = tid; i < BINS; i += NTH) hist[i] = 0u;
                __syncthreads();
                for (int i = tid; i < NBOX; i += NTH) {
                    float s = sraw[(size_t)i * NCLSIN];
                    unsigned k = (s > 0.3f) ? fmap(s) : 0u;
                    if (k) {
                        unsigned long long key =
                            ((unsigned long long)k << 32) | (0xFFFFFFFFu - (unsigned)i);
                        if (key < lastk) {
                            unsigned bin = (kmax - k) >> shift;
                            if (bin < BINS - 1) atomicAdd(&hist[bin], 1u);
                        }
                    }
                }
                __syncthreads();
                bin_select(hist, gbuf, &sh_g, &sh_b, &sh_pb, tid, (unsigned)TSEL);
                if (sh_b < BINS - 1) {
                    long long t = (long long)kmax - ((long long)(sh_b + 1) << shift) + 1;
                    thr = (t < 1) ? 1u : (unsigned)t;
                    break;
                }
            }
        }

        if (tid == 0) sh_cnt = 0;
        __syncthreads();
        for (int i = tid; i < NBOX; i += NTH) {
            float s = sraw[(size_t)i * NCLSIN];
            unsigned k = (s > 0.3f) ? fmap(s) : 0u;
            if (k >= thr) {
                unsigned long long key =
                    ((unsigned long long)k << 32) | (0xFFFFFFFFu - (unsigned)i);
                if (key < lastk) {
                    int pos = atomicAdd(&sh_cnt, 1);
                    if (pos < CAP) cand[pos] = key;
                }
            }
        }
        __syncthreads();
        const int M = sh_cnt < CAP ? sh_cnt : CAP;

        sort_desc(cand, M, tid);
        const int PBX = M < CBCAP ? M : CBCAP;
        for (int i = tid; i < PBX; i += NTH)
            candbox[i] = bbase[(int)(0xFFFFFFFFu - (unsigned)cand[i])];
        __syncthreads();
        walk_slow(cand, 0, M, bbase, candbox, sel0, sel1, sa0, sa1,
                  ss0, ss1, nsel, &sh_nsel, tid);
        if (nsel >= MAXSEL || E <= M) break;
        lastk = cand[M - 1];
        __syncthreads();
    }

    // ---- outputs: selections in greedy order, zero-padded ----
    if (tid < 64) {
        float* scp = ws_sc + (size_t)bc * MAXSEL;
        float4* bxp = (float4*)(ws_bx + (size_t)bc * MAXSEL * 4);
        {
            bool v = tid < nsel;
            scp[tid] = v ? ss0 : 0.f;
            bxp[tid] = v ? sel0 : make_float4(0.f, 0.f, 0.f, 0.f);
        }
        int j1 = tid + 64;
        if (j1 < MAXSEL) {
            bool v = j1 < nsel;
            scp[j1] = v ? ss1 : 0.f;
            bxp[j1] = v ? sel1 : make_float4(0.f, 0.f, 0.f, 0.f);
        }
    }
}

// ---------------------------------------------------------------------------
// Kernel 2: one block per batch: stable top-200 of 9000 via radix-select+sort.
// ---------------------------------------------------------------------------
__global__ __launch_bounds__(NTH) void topk_k(const float* __restrict__ ws_sc,
                                              const float* __restrict__ ws_bx,
                                              float* __restrict__ out_sc,
                                              float* __restrict__ out_bx) {
    __shared__ unsigned hist[BINS];
    __shared__ unsigned gbuf[NTH];
    __shared__ unsigned long long cand[CAP];
    __shared__ unsigned sh_kmax, sh_pb;
    __shared__ int sh_E, sh_g, sh_b, sh_cnt;

    const int tid = threadIdx.x;
    const int b = blockIdx.x;
    const int NF = NCLS * MAXSEL;  // 9000
    const float* sp = ws_sc + (size_t)b * NF;

    unsigned km = 0, ce = 0;
    for (int f = tid; f < NF; f += NTH) {
        unsigned k = __float_as_uint(sp[f]);
        if (k) { ce++; km = km > k ? km : k; }
    }
#pragma unroll
    for (int off = 32; off > 0; off >>= 1) {
        unsigned o = (unsigned)__shfl_xor((int)km, off, 64);
        km = km > o ? km : o;
        ce += (unsigned)__shfl_xor((int)ce, off, 64);
    }
    if ((tid & 63) == 0) { gbuf[tid >> 6] = km; gbuf[8 + (tid >> 6)] = ce; }
    __syncthreads();
    if (tid == 0) {
        unsigned m2 = 0, c2 = 0;
        for (int w = 0; w < NTH / 64; ++w) {
            m2 = m2 > gbuf[w] ? m2 : gbuf[w];
            c2 += gbuf[8 + w];
        }
        sh_kmax = m2; sh_E = (int)c2;
    }
    __syncthreads();
    const int E = sh_E;
    const unsigned kmax = sh_kmax;

    unsigned thr = 1u;
    if (E > TOPK) {
        for (int shift = 8;; shift += 4) {
            for (int i = tid; i < BINS; i += NTH) hist[i] = 0u;
            __syncthreads();
            for (int f = tid; f < NF; f += NTH) {
                unsigned k = __float_as_uint(sp[f]);
                if (k) {
                    unsigned bin = (kmax - k) >> shift;
                    if (bin < BINS - 1) atomicAdd(&hist[bin], 1u);
                }
            }
            __syncthreads();
            bin_select(hist, gbuf, &sh_g, &sh_b, &sh_pb, tid, (unsigned)TOPK);
            if (sh_b < BINS - 1) {
                long long t = (long long)kmax - ((long long)(sh_b + 1) << shift) + 1;
                thr = (t < 1) ? 1u : (unsigned)t;
                break;
            }
        }
    }

    if (tid == 0) sh_cnt = 0;
    __syncthreads();
    for (int f = tid; f < NF; f += NTH) {
        unsigned k = __float_as_uint(sp[f]);
        if (k >= thr) {
            int pos = atomicAdd(&sh_cnt, 1);
            if (pos < CAP)
                cand[pos] = ((unsigned long long)k << 32) | (0xFFFFFFFFu - (unsigned)f);
        }
    }
    __syncthreads();
    int M = sh_cnt < CAP ? sh_cnt : CAP;

    if (M < TOPK) {
        int lim = M + TOPK;
        if (lim > NF) lim = NF;
        for (int f = tid; f < lim; f += NTH) {
            unsigned k = __float_as_uint(sp[f]);
            if (k == 0) {
                int pos = atomicAdd(&sh_cnt, 1);
                if (pos < CAP)
                    cand[pos] = (unsigned long long)(0xFFFFFFFFu - (unsigned)f);
            }
        }
        __syncthreads();
        M = sh_cnt < CAP ? sh_cnt : CAP;
    }

    sort_desc(cand, M, tid);

    for (int k = tid; k < TOPK; k += NTH) {
        float cls = 0.f, s = 0.f;
        float4 bx = make_float4(0.f, 0.f, 0.f, 0.f);
        if (k < M) {
            unsigned long long key = cand[k];
            unsigned f = 0xFFFFFFFFu - (unsigned)key;
            s = __uint_as_float((unsigned)(key >> 32));
            cls = (s > 0.f) ? (float)(f / MAXSEL + 1) : 0.f;
            bx = *(const float4*)(ws_bx + ((size_t)b * NF + f) * 4);
        }
        out_sc[((size_t)b * TOPK + k) * 2 + 0] = cls;
        out_sc[((size_t)b * TOPK + k) * 2 + 1] = s;
        ((float4*)out_bx)[(size_t)b * TOPK + k] = bx;
    }
}

// ---------------------------------------------------------------------------
extern "C" void kernel_launch(void* const* d_in, const int* in_sizes, int n_in,
                              void* d_out, int out_size, void* d_ws, size_t ws_size,
                              hipStream_t stream) {
    const float* scores = (const float*)d_in[0];
    const float4* boxes = (const float4*)d_in[1];
    float* out = (float*)d_out;

    const int B = in_sizes[1] / (NBOX * 4);
    const int NBC = B * NCLS;

    // ws layout: cnt [NBC * CNTSTR ints, 64B-padded] | cand [NBC*CAP u64] | sc | bx
    size_t off_cand = ((size_t)NBC * CNTSTR * 4 + 15) & ~(size_t)15;
    size_t off_sc = off_cand + (size_t)NBC * CAP * 8;
    size_t off_bx = off_sc + (size_t)NBC * MAXSEL * 4;
    size_t need = off_bx + (size_t)NBC * MAXSEL * 16;

    char* ws = (char*)d_ws;
    bool use_band = ws_size >= need;

    int* cnt_g;
    unsigned long long* cand_g;
    float *ws_sc, *ws_bx;
    if (use_band) {
        cnt_g = (int*)ws;
        cand_g = (unsigned long long*)(ws + off_cand);
        ws_sc = (float*)(ws + off_sc);
        ws_bx = (float*)(ws + off_bx);
    } else {
        cnt_g = (int*)ws;                  // unused
        cand_g = (unsigned long long*)ws;  // unused
        ws_sc = (float*)ws;
        ws_bx = ws_sc + (size_t)NBC * MAXSEL;
    }

    if (use_band) {
        hipMemsetAsync(cnt_g, 0, (size_t)NBC * CNTSTR * 4, stream);
        filter_k<<<dim3(NBOX / BOXPB, B), NTH, 0, stream>>>(scores, cand_g, cnt_g);
    }
    nms_k<<<dim3(NCLS, B), NTH, 0, stream>>>(cand_g, cnt_g, scores, boxes,
                                             ws_sc, ws_bx, use_band ? 1 : 0);
    topk_k<<<B, NTH, 0, stream>>>(ws_sc, ws_bx, out, out + (size_t)B * TOPK * 2);
}